// Round 12
// baseline (304.780 us; speedup 1.0000x reference)
//
#include <hip/hip_runtime.h>

typedef __attribute__((ext_vector_type(8))) short short8;
typedef __attribute__((ext_vector_type(4))) float float4v;

#define CDIM 256
#define NQ   8192
#define HWN  9216

static __device__ __forceinline__ unsigned short f2bf(float f) {
  union { float f; unsigned int i; } v; v.f = f;
  unsigned int r = v.i + 0x7FFFu + ((v.i >> 16) & 1u);
  return (unsigned short)(r >> 16);
}

// ---------------- fused stats: blocks 0-255 q-partials, 256-511 k-channels ----------------
__global__ __launch_bounds__(256) void stats_all_kernel(const float* __restrict__ q, const float* __restrict__ k0,
                                                        float* __restrict__ pq, float* __restrict__ pq2,
                                                        float* __restrict__ mk, float* __restrict__ rk,
                                                        float* __restrict__ sdk) {
  int b = blockIdx.x, t = threadIdx.x;
  if (b < 256) {
    const float4* q4 = (const float4*)(q + (size_t)b * 32 * CDIM);
    float sx = 0, sy = 0, sz = 0, sw = 0, tx = 0, ty = 0, tz = 0, tw = 0;
    for (int i = t; i < 32 * 64; i += 256) {
      float4 v = q4[i];
      sx += v.x; sy += v.y; sz += v.z; sw += v.w;
      tx += v.x * v.x; ty += v.y * v.y; tz += v.z * v.z; tw += v.w * v.w;
    }
    __shared__ float4 sA[256], sB[256];
    sA[t] = make_float4(sx, sy, sz, sw); sB[t] = make_float4(tx, ty, tz, tw);
    __syncthreads();
    if (t < 64) {
      float4 a = sA[t], b2 = sB[t];
      #pragma unroll
      for (int r = 1; r < 4; r++) {
        float4 u = sA[t + r * 64], w2 = sB[t + r * 64];
        a.x += u.x; a.y += u.y; a.z += u.z; a.w += u.w;
        b2.x += w2.x; b2.y += w2.y; b2.z += w2.z; b2.w += w2.w;
      }
      ((float4*)pq)[b * 64 + t] = a;
      ((float4*)pq2)[b * 64 + t] = b2;
    }
  } else {
    __shared__ float rs[256], rs2[256];
    int c = b - 256;
    float s = 0.f, s2 = 0.f;
    const float4* row = (const float4*)(k0 + (size_t)c * HWN);
    for (int j = t; j < HWN / 4; j += 256) {
      float4 v = row[j];
      s += v.x + v.y + v.z + v.w;
      s2 += v.x * v.x + v.y * v.y + v.z * v.z + v.w * v.w;
    }
    rs[t] = s; rs2[t] = s2; __syncthreads();
    for (int off = 128; off > 0; off >>= 1) {
      if (t < off) { rs[t] += rs[t + off]; rs2[t] += rs2[t + off]; }
      __syncthreads();
    }
    if (t == 0) {
      float mean = rs[0] / (float)HWN;
      float var = fmaxf(rs2[0] / (float)HWN - mean * mean, 0.f);
      mk[c] = mean; rk[c] = rsqrtf(var + 1e-5f); sdk[c] = sqrtf(var + 1e-5f);
    }
  }
}

// ---------------- cvts + q-finalize + style bias fold ----------------
__global__ __launch_bounds__(256) void cvtall_kernel(const float* __restrict__ qw, const float* __restrict__ kw,
                                                     const float* __restrict__ sw, const float* __restrict__ sb,
                                                     unsigned short* __restrict__ qwb, unsigned short* __restrict__ kwb,
                                                     unsigned short* __restrict__ swb2,
                                                     const float* __restrict__ sdk, const float* __restrict__ mk,
                                                     const float* __restrict__ pq, const float* __restrict__ pq2,
                                                     float* __restrict__ mq, float* __restrict__ rq,
                                                     float* __restrict__ bias2) {
  int b = blockIdx.x, t = threadIdx.x;
  if (b < 128) {
    const float* src = b < 64 ? qw : kw;
    unsigned short* dst = b < 64 ? qwb : kwb;
    int i = (b & 63) * 256 + t;
    float4 v = ((const float4*)src)[i];
    union { unsigned short o[4]; uint2 u; } w;
    w.o[0] = f2bf(v.x); w.o[1] = f2bf(v.y); w.o[2] = f2bf(v.z); w.o[3] = f2bf(v.w);
    ((uint2*)dst)[i] = w.u;
  } else if (b < 192) {
    int i = (b - 128) * 256 + t;
    int c0 = (i * 4) & 255;
    float4 v = ((const float4*)sw)[i];
    union { unsigned short o[4]; uint2 u; } w;
    w.o[0] = f2bf(v.x * sdk[c0 + 0]); w.o[1] = f2bf(v.y * sdk[c0 + 1]);
    w.o[2] = f2bf(v.z * sdk[c0 + 2]); w.o[3] = f2bf(v.w * sdk[c0 + 3]);
    ((uint2*)swb2)[i] = w.u;
  } else if (b == 192) {
    int c = t;
    float s = 0, s2 = 0;
    for (int bb = 0; bb < 256; bb++) { s += pq[bb * 256 + c]; s2 += pq2[bb * 256 + c]; }
    float mean = s / (float)NQ;
    float var = s2 / (float)NQ - mean * mean;
    mq[c] = mean; rq[c] = rsqrtf(fmaxf(var, 0.f) + 1e-5f);
  } else {
    int r = t;
    float acc = 0.f;
    for (int k = 0; k < 256; k++) acc += sw[r * 256 + k] * mk[k];
    bias2[r] = acc + sb[r];
  }
}

// ---------------- transpose k (C,HW) f32 -> stn (HW,C) bf16 normalized ----------------
__global__ __launch_bounds__(256) void ktrans_kernel(const float* __restrict__ k0,
                                                     const float* __restrict__ mk, const float* __restrict__ rk,
                                                     unsigned short* __restrict__ stn) {
  __shared__ float tile[32][33];
  int p0 = blockIdx.x * 32, c0 = blockIdx.y * 32;
  int t = threadIdx.x;
  int pl = t & 31, cl = t >> 5;
  #pragma unroll
  for (int r = 0; r < 4; r++) {
    int c = cl + r * 8;
    tile[c][pl] = k0[(size_t)(c0 + c) * HWN + p0 + pl];
  }
  __syncthreads();
  int cl2 = t & 31, pl2 = t >> 5;
  float mean = mk[c0 + cl2], rinv = rk[c0 + cl2];
  #pragma unroll
  for (int r = 0; r < 4; r++) {
    int p = pl2 + r * 8;
    float f = tile[cl2][p];
    stn[(size_t)(p0 + p) * CDIM + c0 + cl2] = f2bf((f - mean) * rinv);
  }
}

// ---------------- mega-GEMM: blocks [0,128) Qs; [128,272) Km; [272,416) se/se^2 ----------------
__global__ __launch_bounds__(256) void gemms_kernel(const float* __restrict__ qf,
                                                    const float* __restrict__ mq, const float* __restrict__ rq,
                                                    const unsigned short* __restrict__ qwb, const float* __restrict__ qb,
                                                    unsigned short* __restrict__ Qs,
                                                    const unsigned short* __restrict__ stn,
                                                    const unsigned short* __restrict__ kwb, const float* __restrict__ kb,
                                                    unsigned short* __restrict__ Km,
                                                    const unsigned short* __restrict__ swb2, const float* __restrict__ bias2,
                                                    unsigned short* __restrict__ VseT, unsigned short* __restrict__ Vse2T) {
  int b = blockIdx.x, t = threadIdx.x;
  int w = t >> 6, lane = t & 63, g = lane >> 4, li = lane & 15;
  float4v acc[16];
  #pragma unroll
  for (int i = 0; i < 16; i++) acc[i] = (float4v){0.f, 0.f, 0.f, 0.f};

  if (b < 128) {
    int m0 = b * 64;
    const float* abase = qf + (size_t)(m0 + w * 16 + li) * CDIM + g * 8;
    #pragma unroll
    for (int kc = 0; kc < 8; kc++) {
      int c0 = kc * 32 + g * 8;
      float4 f0 = *(const float4*)(abase + kc * 32);
      float4 f1 = *(const float4*)(abase + kc * 32 + 4);
      float4 m0v = *(const float4*)(mq + c0), m1v = *(const float4*)(mq + c0 + 4);
      float4 r0v = *(const float4*)(rq + c0), r1v = *(const float4*)(rq + c0 + 4);
      union { unsigned short o[8]; short8 s; } a;
      a.o[0] = f2bf((f0.x - m0v.x) * r0v.x); a.o[1] = f2bf((f0.y - m0v.y) * r0v.y);
      a.o[2] = f2bf((f0.z - m0v.z) * r0v.z); a.o[3] = f2bf((f0.w - m0v.w) * r0v.w);
      a.o[4] = f2bf((f1.x - m1v.x) * r1v.x); a.o[5] = f2bf((f1.y - m1v.y) * r1v.y);
      a.o[6] = f2bf((f1.z - m1v.z) * r1v.z); a.o[7] = f2bf((f1.w - m1v.w) * r1v.w);
      #pragma unroll
      for (int ct = 0; ct < 16; ct++) {
        short8 bb = *(const short8*)(qwb + (size_t)(ct * 16 + li) * CDIM + kc * 32 + g * 8);
        acc[ct] = __builtin_amdgcn_mfma_f32_16x16x32_bf16(a.s, bb, acc[ct], 0, 0, 0);
      }
    }
    #pragma unroll
    for (int ct = 0; ct < 16; ct++) {
      int col = ct * 16 + li;
      #pragma unroll
      for (int j = 0; j < 4; j++) {
        int row = m0 + w * 16 + g * 4 + j;
        float v = (acc[ct][j] + qb[col]) * (0.0625f * 1.4426950408889634f);
        Qs[(size_t)row * CDIM + col] = f2bf(v);
      }
    }
  } else if (b < 272) {
    int m0 = (b - 128) * 64;
    const unsigned short* abase = stn + (size_t)(m0 + w * 16 + li) * CDIM + g * 8;
    #pragma unroll
    for (int kc = 0; kc < 8; kc++) {
      short8 a = *(const short8*)(abase + kc * 32);
      #pragma unroll
      for (int ct = 0; ct < 16; ct++) {
        short8 bb = *(const short8*)(kwb + (size_t)(ct * 16 + li) * CDIM + kc * 32 + g * 8);
        acc[ct] = __builtin_amdgcn_mfma_f32_16x16x32_bf16(a, bb, acc[ct], 0, 0, 0);
      }
    }
    #pragma unroll
    for (int ct = 0; ct < 16; ct++) {
      int col = ct * 16 + li;
      #pragma unroll
      for (int j = 0; j < 4; j++) {
        int row = m0 + w * 16 + g * 4 + j;
        Km[(size_t)row * CDIM + col] = f2bf(acc[ct][j] + kb[col]);
      }
    }
  } else {
    int bb2 = b - 272;
    int m0 = (bb2 & 3) * 64, n0 = (bb2 >> 2) * 256;
    const unsigned short* abase = swb2 + (size_t)(m0 + w * 16 + li) * CDIM + g * 8;
    #pragma unroll
    for (int kc = 0; kc < 8; kc++) {
      short8 a = *(const short8*)(abase + kc * 32);
      #pragma unroll
      for (int ct = 0; ct < 16; ct++) {
        short8 bb = *(const short8*)(stn + (size_t)(n0 + ct * 16 + li) * CDIM + kc * 32 + g * 8);
        acc[ct] = __builtin_amdgcn_mfma_f32_16x16x32_bf16(a, bb, acc[ct], 0, 0, 0);
      }
    }
    #pragma unroll
    for (int ct = 0; ct < 16; ct++) {
      int col = n0 + ct * 16 + li;
      #pragma unroll
      for (int j = 0; j < 4; j++) {
        int row = m0 + w * 16 + g * 4 + j;
        float v = acc[ct][j] + bias2[row];
        VseT[(size_t)row * HWN + col] = f2bf(v);
        Vse2T[(size_t)row * HWN + col] = f2bf(v * v);
      }
    }
  }
}

// ---------------- split-K flash attention: independent-rows waves, 1 barrier/iter ----------------
static __device__ __forceinline__ void issue_K(int p0, int w, int lane,
                                               const unsigned short* __restrict__ Km,
                                               unsigned short* K_buf) {
  #pragma unroll
  for (int j2 = 0; j2 < 2; j2++) {
    int i16 = (j2 * 8 + w) * 64 + lane;
    int row = i16 >> 5;
    int chc = (i16 & 31) ^ (row & 15);
    const unsigned short* src = Km + (size_t)(p0 + row) * CDIM + chc * 8;
    unsigned short* dst = K_buf + (j2 * 8 + w) * 512;
    __builtin_amdgcn_global_load_lds((const __attribute__((address_space(1))) unsigned int*)src,
                                     (__attribute__((address_space(3))) unsigned int*)dst, 16, 0, 0);
  }
}

static __device__ __forceinline__ void issue_V(int p0, int w, int lane,
                                               const unsigned short* __restrict__ VseT,
                                               const unsigned short* __restrict__ Vse2T,
                                               unsigned short* V_buf) {
  #pragma unroll
  for (int j2 = 0; j2 < 4; j2++) {
    int i16 = (j2 * 8 + w) * 64 + lane;
    int vd = i16 >> 2;
    int gc = (i16 & 3) ^ ((vd ^ (vd >> 2)) & 3);        // involutive bank swizzle
    const unsigned short* src = (vd < 256 ? VseT + (size_t)vd * HWN
                                          : Vse2T + (size_t)(vd - 256) * HWN) + p0 + gc * 8;
    unsigned short* dst = V_buf + (j2 * 8 + w) * 512;
    __builtin_amdgcn_global_load_lds((const __attribute__((address_space(1))) unsigned int*)src,
                                     (__attribute__((address_space(3))) unsigned int*)dst, 16, 0, 0);
  }
}

__global__ __launch_bounds__(512, 1) void attn_kernel(const unsigned short* __restrict__ Qs,
                                                      const unsigned short* __restrict__ Km,
                                                      const unsigned short* __restrict__ VseT,
                                                      const unsigned short* __restrict__ Vse2T,
                                                      float* __restrict__ Op, float2* __restrict__ ml,
                                                      int tiles_per_g, int G) {
  __shared__ __align__(16) unsigned short K_lds[2][32 * 256];   // 16KB x2
  __shared__ __align__(16) unsigned short V_lds[2][512 * 32];   // 32KB x2
  __shared__ __align__(16) unsigned short P_scr[8 * 640];       // per-wave 16x(32+pad8)

  const int t = threadIdx.x;
  const int w = t >> 6, lane = t & 63;
  const int g4 = lane >> 4, li = lane & 15;

  int bid = blockIdx.x, qb, g;
  if (G == 4) { g = (bid & 7) >> 1; qb = ((bid & 1) << 5) + (bid >> 3); }
  else        { g = bid % G;        qb = bid / G; }
  const int n0 = qb * 128;
  const int p_begin = g * tiles_per_g * 32;

  short8 qf[8];
  {
    const unsigned short* qbase = Qs + (size_t)(n0 + w * 16 + li) * CDIM + g4 * 8;
    #pragma unroll
    for (int kc = 0; kc < 8; kc++) qf[kc] = *(const short8*)(qbase + kc * 32);
  }
  float4v O[32];   // 16 own rows x 512 vd (32 tiles of 16x16)
  #pragma unroll
  for (int i = 0; i < 32; i++) O[i] = (float4v){0.f, 0.f, 0.f, 0.f};
  float4v s_acc = (float4v){0.f, 0.f, 0.f, 0.f};
  float m[4] = {-1e30f, -1e30f, -1e30f, -1e30f};
  const short8 ones = (short8){0x3F80, 0x3F80, 0x3F80, 0x3F80, 0x3F80, 0x3F80, 0x3F80, 0x3F80};

  issue_K(p_begin, w, lane, Km, K_lds[0]);
  issue_V(p_begin, w, lane, VseT, Vse2T, V_lds[0]);

  for (int it = 0; it < tiles_per_g; ++it) {
    asm volatile("s_waitcnt vmcnt(0)" ::: "memory");   // own stage(t) loads landed (issued 1 iter ago)
    __builtin_amdgcn_s_barrier();                      // all waves' stage(t) landed; all t-1 reads done
    asm volatile("" ::: "memory");
    if (it + 1 < tiles_per_g) {                        // stage t+1 into the buffer freed above
      issue_K(p_begin + (it + 1) * 32, w, lane, Km, K_lds[(it + 1) & 1]);
      issue_V(p_begin + (it + 1) * 32, w, lane, VseT, Vse2T, V_lds[(it + 1) & 1]);
    }

    // --- QK(t): own 16 rows x 32 keys (exp2 domain) ---
    const unsigned short* Kc = K_lds[it & 1];
    float4v S0 = (float4v){0.f, 0.f, 0.f, 0.f}, S1 = (float4v){0.f, 0.f, 0.f, 0.f};
    __builtin_amdgcn_s_setprio(1);
    #pragma unroll
    for (int kc = 0; kc < 8; kc++) {
      int c = kc * 4 + g4;
      short8 b0 = *(const short8*)((const char*)Kc + li * 512 + ((c ^ li) << 4));
      short8 b1 = *(const short8*)((const char*)Kc + (16 + li) * 512 + ((c ^ li) << 4));
      S0 = __builtin_amdgcn_mfma_f32_16x16x32_bf16(qf[kc], b0, S0, 0, 0, 0);
      S1 = __builtin_amdgcn_mfma_f32_16x16x32_bf16(qf[kc], b1, S1, 0, 0, 0);
    }
    __builtin_amdgcn_s_setprio(0);

    // --- in-wave softmax (defer-max THR=5 in log2 units) ---
    float pmax[4], corr[4];
    #pragma unroll
    for (int j = 0; j < 4; j++) {
      float mx = fmaxf(S0[j], S1[j]);
      #pragma unroll
      for (int msk = 1; msk < 16; msk <<= 1) mx = fmaxf(mx, __shfl_xor(mx, msk, 64));
      pmax[j] = mx;
    }
    int needs = ((pmax[0] > m[0] + 5.f) || (pmax[1] > m[1] + 5.f) ||
                 (pmax[2] > m[2] + 5.f) || (pmax[3] > m[3] + 5.f)) ? 1 : 0;
    if (needs) {
      #pragma unroll
      for (int j = 0; j < 4; j++) {
        float mn = fmaxf(m[j], pmax[j]);
        corr[j] = exp2f(m[j] - mn);
        m[j] = mn;
      }
    }
    unsigned short* Pw = P_scr + w * 640;
    #pragma unroll
    for (int j = 0; j < 4; j++) {
      float e0 = exp2f(S0[j] - m[j]);
      float e1 = exp2f(S1[j] - m[j]);
      int row = g4 * 4 + j;
      Pw[row * 40 + li] = f2bf(e0);
      Pw[row * 40 + 16 + li] = f2bf(e1);
    }
    if (__any(needs)) {      // wave-local rescale (own rows only)
      #pragma unroll
      for (int j = 0; j < 4; j++) s_acc[j] *= corr[j];
      #pragma unroll
      for (int i = 0; i < 32; i++) {
        O[i][0] *= corr[0]; O[i][1] *= corr[1]; O[i][2] *= corr[2]; O[i][3] *= corr[3];
      }
    }

    // --- PV(t): own rows x all 512 vd; P from own scratch (in-wave in-order LDS) ---
    short8 pa = *(const short8*)(Pw + li * 40 + g4 * 8);
    const unsigned short* Vc = V_lds[it & 1];
    __builtin_amdgcn_s_setprio(1);
    s_acc = __builtin_amdgcn_mfma_f32_16x16x32_bf16(pa, ones, s_acc, 0, 0, 0);
    #pragma unroll
    for (int vt = 0; vt < 32; vt++) {
      int vd = vt * 16 + li;
      int kc2 = g4 ^ ((vd ^ (vd >> 2)) & 3);
      short8 vb = *(const short8*)((const char*)Vc + vd * 64 + (kc2 << 4));
      O[vt] = __builtin_amdgcn_mfma_f32_16x16x32_bf16(pa, vb, O[vt], 0, 0, 0);
    }
    __builtin_amdgcn_s_setprio(0);
  }

  // write partials: Op[g][n][vd] (f32, unnormalized), ml[g][n] = (m [log2], s)
  #pragma unroll
  for (int vt = 0; vt < 32; vt++) {
    #pragma unroll
    for (int j = 0; j < 4; j++) {
      int n = n0 + w * 16 + g4 * 4 + j;
      int vd = vt * 16 + li;
      Op[((size_t)g * NQ + n) * 512 + vd] = O[vt][j];
    }
  }
  if (li == 0) {
    #pragma unroll
    for (int j = 0; j < 4; j++) {
      int n = n0 + w * 16 + g4 * 4 + j;
      ml[(size_t)g * NQ + n] = make_float2(m[j], s_acc[j]);
    }
  }
}

// ---------------- combine (float4) + AdaAttN epilogue (exp2 domain) ----------------
__global__ __launch_bounds__(256) void combine_kernel(const float* __restrict__ Op, const float2* __restrict__ ml,
                                                      const float* __restrict__ q,
                                                      const float* __restrict__ mq, const float* __restrict__ rq,
                                                      float* __restrict__ out, int G) {
  int t = threadIdx.x;
  int rl = t >> 6, j = t & 63;
  int n = blockIdx.x * 4 + rl, c0 = j * 4;
  __shared__ float wsm[4][8];
  if (j == 0) {
    float mstar = -1e30f;
    float mg[8], lg[8];
    for (int g = 0; g < G; g++) {
      float2 v = ml[(size_t)g * NQ + n];
      mg[g] = v.x; lg[g] = v.y;
      mstar = fmaxf(mstar, v.x);
    }
    float L = 0.f;
    for (int g = 0; g < G; g++) L += lg[g] * exp2f(mg[g] - mstar);
    float Li = 1.f / L;
    for (int g = 0; g < G; g++) wsm[rl][g] = exp2f(mg[g] - mstar) * Li;
  }
  __syncthreads();
  float4 of = make_float4(0, 0, 0, 0), o2 = make_float4(0, 0, 0, 0);
  for (int g = 0; g < G; g++) {
    size_t base = ((size_t)g * NQ + n) * 512;
    float wg = wsm[rl][g];
    float4 a = *(const float4*)(Op + base + c0);
    float4 b = *(const float4*)(Op + base + 256 + c0);
    of.x += wg * a.x; of.y += wg * a.y; of.z += wg * a.z; of.w += wg * a.w;
    o2.x += wg * b.x; o2.y += wg * b.y; o2.z += wg * b.z; o2.w += wg * b.w;
  }
  float4 qv = *(const float4*)(q + (size_t)n * CDIM + c0);
  float4 mv = *(const float4*)(mq + c0);
  float4 rv = *(const float4*)(rq + c0);
  float4 ov;
  ov.x = (qv.x - mv.x) * rv.x * sqrtf(fmaxf(o2.x - of.x * of.x, 0.f)) + of.x;
  ov.y = (qv.y - mv.y) * rv.y * sqrtf(fmaxf(o2.y - of.y * of.y, 0.f)) + of.y;
  ov.z = (qv.z - mv.z) * rv.z * sqrtf(fmaxf(o2.z - of.z * of.z, 0.f)) + of.z;
  ov.w = (qv.w - mv.w) * rv.w * sqrtf(fmaxf(o2.w - of.w * of.w, 0.f)) + of.w;
  *(float4*)(out + (size_t)n * CDIM + c0) = ov;
}

extern "C" void kernel_launch(void* const* d_in, const int* in_sizes, int n_in,
                              void* d_out, int out_size, void* d_ws, size_t ws_size,
                              hipStream_t stream) {
  const float* q  = (const float*)d_in[0];
  const float* k0 = (const float*)d_in[1];
  const float* qw = (const float*)d_in[2];
  const float* qb = (const float*)d_in[3];
  const float* kw = (const float*)d_in[4];
  const float* kb = (const float*)d_in[5];
  const float* sw = (const float*)d_in[6];
  const float* sb = (const float*)d_in[7];
  float* out = (float*)d_out;

  char* ws = (char*)d_ws;
  float* mq   = (float*)ws; ws += 1024;
  float* rq   = (float*)ws; ws += 1024;
  float* mk   = (float*)ws; ws += 1024;
  float* rk   = (float*)ws; ws += 1024;
  float* sdk  = (float*)ws; ws += 1024;
  float* bias2= (float*)ws; ws += 1024;
  float* pq   = (float*)ws; ws += 256 * 256 * 4;
  float* pq2  = (float*)ws; ws += 256 * 256 * 4;
  unsigned short* qwb  = (unsigned short*)ws; ws += 65536 * 2;
  unsigned short* kwb  = (unsigned short*)ws; ws += 65536 * 2;
  unsigned short* swb2 = (unsigned short*)ws; ws += 65536 * 2;
  unsigned short* Qs    = (unsigned short*)ws; ws += (size_t)NQ * CDIM * 2;
  unsigned short* stn   = (unsigned short*)ws; ws += (size_t)HWN * CDIM * 2;
  unsigned short* Km    = (unsigned short*)ws; ws += (size_t)HWN * CDIM * 2;
  unsigned short* VseT  = (unsigned short*)ws; ws += (size_t)HWN * CDIM * 2;
  unsigned short* Vse2T = (unsigned short*)ws; ws += (size_t)HWN * CDIM * 2;

  size_t base_used = (size_t)(ws - (char*)d_ws);
  int G = 4;
  const int gcand[3] = {4, 2, 1};
  for (int i = 0; i < 3; i++) {
    G = gcand[i];
    size_t need = base_used + (size_t)G * ((size_t)NQ * 512 * 4 + (size_t)NQ * 8);
    if (need <= ws_size) break;
  }
  float*  Opart = (float*)ws;                 ws += (size_t)G * NQ * 512 * 4;
  float2* mlp   = (float2*)ws;                ws += (size_t)G * NQ * 8;
  int tiles_per_g = (HWN / 32) / G;

  stats_all_kernel<<<512, 256, 0, stream>>>(q, k0, pq, pq2, mk, rk, sdk);
  cvtall_kernel<<<194, 256, 0, stream>>>(qw, kw, sw, sb, qwb, kwb, swb2, sdk, mk, pq, pq2, mq, rq, bias2);
  ktrans_kernel<<<dim3(HWN / 32, CDIM / 32), 256, 0, stream>>>(k0, mk, rk, stn);
  gemms_kernel<<<416, 256, 0, stream>>>(q, mq, rq, qwb, qb, Qs, stn, kwb, kb, Km, swb2, bias2, VseT, Vse2T);
  attn_kernel<<<dim3(64 * G), 512, 0, stream>>>(Qs, Km, VseT, Vse2T, Opart, mlp, tiles_per_g, G);
  combine_kernel<<<NQ / 4, 256, 0, stream>>>(Opart, mlp, q, mq, rq, out, G);
}

// Round 13
// 286.968 us; speedup vs baseline: 1.0621x; 1.0621x over previous
//
#include <hip/hip_runtime.h>

typedef __attribute__((ext_vector_type(8))) short short8;
typedef __attribute__((ext_vector_type(4))) float float4v;

#define CDIM 256
#define NQ   8192
#define HWN  9216

static __device__ __forceinline__ unsigned short f2bf(float f) {
  union { float f; unsigned int i; } v; v.f = f;
  unsigned int r = v.i + 0x7FFFu + ((v.i >> 16) & 1u);
  return (unsigned short)(r >> 16);
}

// ---------------- fused stats: blocks 0-255 q-partials, 256-511 k-channels ----------------
__global__ __launch_bounds__(256) void stats_all_kernel(const float* __restrict__ q, const float* __restrict__ k0,
                                                        float* __restrict__ pq, float* __restrict__ pq2,
                                                        float* __restrict__ mk, float* __restrict__ rk) {
  int b = blockIdx.x, t = threadIdx.x;
  if (b < 256) {
    const float4* q4 = (const float4*)(q + (size_t)b * 32 * CDIM);
    float sx = 0, sy = 0, sz = 0, sw = 0, tx = 0, ty = 0, tz = 0, tw = 0;
    for (int i = t; i < 32 * 64; i += 256) {
      float4 v = q4[i];
      sx += v.x; sy += v.y; sz += v.z; sw += v.w;
      tx += v.x * v.x; ty += v.y * v.y; tz += v.z * v.z; tw += v.w * v.w;
    }
    __shared__ float4 sA[256], sB[256];
    sA[t] = make_float4(sx, sy, sz, sw); sB[t] = make_float4(tx, ty, tz, tw);
    __syncthreads();
    if (t < 64) {
      float4 a = sA[t], b2 = sB[t];
      #pragma unroll
      for (int r = 1; r < 4; r++) {
        float4 u = sA[t + r * 64], w2 = sB[t + r * 64];
        a.x += u.x; a.y += u.y; a.z += u.z; a.w += u.w;
        b2.x += w2.x; b2.y += w2.y; b2.z += w2.z; b2.w += w2.w;
      }
      ((float4*)pq)[b * 64 + t] = a;
      ((float4*)pq2)[b * 64 + t] = b2;
    }
  } else {
    __shared__ float rs[256], rs2[256];
    int c = b - 256;
    float s = 0.f, s2 = 0.f;
    const float4* row = (const float4*)(k0 + (size_t)c * HWN);
    for (int j = t; j < HWN / 4; j += 256) {
      float4 v = row[j];
      s += v.x + v.y + v.z + v.w;
      s2 += v.x * v.x + v.y * v.y + v.z * v.z + v.w * v.w;
    }
    rs[t] = s; rs2[t] = s2; __syncthreads();
    for (int off = 128; off > 0; off >>= 1) {
      if (t < off) { rs[t] += rs[t + off]; rs2[t] += rs2[t + off]; }
      __syncthreads();
    }
    if (t == 0) {
      float mean = rs[0] / (float)HWN;
      float var = fmaxf(rs2[0] / (float)HWN - mean * mean, 0.f);
      mk[c] = mean; rk[c] = rsqrtf(var + 1e-5f);
    }
  }
}

// ---------------- cvts (plain, unfolded) + q-stats finalize ----------------
__global__ __launch_bounds__(256) void cvtall_kernel(const float* __restrict__ qw, const float* __restrict__ kw,
                                                     const float* __restrict__ sw,
                                                     unsigned short* __restrict__ qwb, unsigned short* __restrict__ kwb,
                                                     unsigned short* __restrict__ swb,
                                                     const float* __restrict__ pq, const float* __restrict__ pq2,
                                                     float* __restrict__ mq, float* __restrict__ rq) {
  int b = blockIdx.x, t = threadIdx.x;
  if (b < 192) {
    const float* src = b < 64 ? qw : (b < 128 ? kw : sw);
    unsigned short* dst = b < 64 ? qwb : (b < 128 ? kwb : swb);
    int i = (b & 63) * 256 + t;
    float4 v = ((const float4*)src)[i];
    union { unsigned short o[4]; uint2 u; } w;
    w.o[0] = f2bf(v.x); w.o[1] = f2bf(v.y); w.o[2] = f2bf(v.z); w.o[3] = f2bf(v.w);
    ((uint2*)dst)[i] = w.u;
  } else {
    int c = t;
    float s = 0, s2 = 0;
    for (int bb = 0; bb < 256; bb++) { s += pq[bb * 256 + c]; s2 += pq2[bb * 256 + c]; }
    float mean = s / (float)NQ;
    float var = s2 / (float)NQ - mean * mean;
    mq[c] = mean; rq[c] = rsqrtf(fmaxf(var, 0.f) + 1e-5f);
  }
}

// ---------------- transpose k (C,HW) f32 -> stT (HW,C) bf16 raw + stn normalized ----------------
__global__ __launch_bounds__(256) void ktrans_kernel(const float* __restrict__ k0,
                                                     const float* __restrict__ mk, const float* __restrict__ rk,
                                                     unsigned short* __restrict__ stT, unsigned short* __restrict__ stn) {
  __shared__ float tile[32][33];
  int p0 = blockIdx.x * 32, c0 = blockIdx.y * 32;
  int t = threadIdx.x;
  int pl = t & 31, cl = t >> 5;
  #pragma unroll
  for (int r = 0; r < 4; r++) {
    int c = cl + r * 8;
    tile[c][pl] = k0[(size_t)(c0 + c) * HWN + p0 + pl];
  }
  __syncthreads();
  int cl2 = t & 31, pl2 = t >> 5;
  float mean = mk[c0 + cl2], rinv = rk[c0 + cl2];
  #pragma unroll
  for (int r = 0; r < 4; r++) {
    int p = pl2 + r * 8;
    float f = tile[cl2][p];
    stT[(size_t)(p0 + p) * CDIM + c0 + cl2] = f2bf(f);
    stn[(size_t)(p0 + p) * CDIM + c0 + cl2] = f2bf((f - mean) * rinv);
  }
}

// ---------------- mega-GEMM: blocks [0,128) Qs; [128,272) Km; [272,416) se/se^2 (unfolded) ----------------
__global__ __launch_bounds__(256) void gemms_kernel(const float* __restrict__ qf,
                                                    const float* __restrict__ mq, const float* __restrict__ rq,
                                                    const unsigned short* __restrict__ qwb, const float* __restrict__ qb,
                                                    unsigned short* __restrict__ Qs,
                                                    const unsigned short* __restrict__ stn,
                                                    const unsigned short* __restrict__ kwb, const float* __restrict__ kb,
                                                    unsigned short* __restrict__ Km,
                                                    const unsigned short* __restrict__ swb, const float* __restrict__ sbf,
                                                    const unsigned short* __restrict__ stT,
                                                    unsigned short* __restrict__ VseT, unsigned short* __restrict__ Vse2T) {
  int b = blockIdx.x, t = threadIdx.x;
  int w = t >> 6, lane = t & 63, g = lane >> 4, li = lane & 15;
  float4v acc[16];
  #pragma unroll
  for (int i = 0; i < 16; i++) acc[i] = (float4v){0.f, 0.f, 0.f, 0.f};

  if (b < 128) {
    int m0 = b * 64;
    const float* abase = qf + (size_t)(m0 + w * 16 + li) * CDIM + g * 8;
    #pragma unroll
    for (int kc = 0; kc < 8; kc++) {
      int c0 = kc * 32 + g * 8;
      float4 f0 = *(const float4*)(abase + kc * 32);
      float4 f1 = *(const float4*)(abase + kc * 32 + 4);
      float4 m0v = *(const float4*)(mq + c0), m1v = *(const float4*)(mq + c0 + 4);
      float4 r0v = *(const float4*)(rq + c0), r1v = *(const float4*)(rq + c0 + 4);
      union { unsigned short o[8]; short8 s; } a;
      a.o[0] = f2bf((f0.x - m0v.x) * r0v.x); a.o[1] = f2bf((f0.y - m0v.y) * r0v.y);
      a.o[2] = f2bf((f0.z - m0v.z) * r0v.z); a.o[3] = f2bf((f0.w - m0v.w) * r0v.w);
      a.o[4] = f2bf((f1.x - m1v.x) * r1v.x); a.o[5] = f2bf((f1.y - m1v.y) * r1v.y);
      a.o[6] = f2bf((f1.z - m1v.z) * r1v.z); a.o[7] = f2bf((f1.w - m1v.w) * r1v.w);
      #pragma unroll
      for (int ct = 0; ct < 16; ct++) {
        short8 bb = *(const short8*)(qwb + (size_t)(ct * 16 + li) * CDIM + kc * 32 + g * 8);
        acc[ct] = __builtin_amdgcn_mfma_f32_16x16x32_bf16(a.s, bb, acc[ct], 0, 0, 0);
      }
    }
    #pragma unroll
    for (int ct = 0; ct < 16; ct++) {
      int col = ct * 16 + li;
      #pragma unroll
      for (int j = 0; j < 4; j++) {
        int row = m0 + w * 16 + g * 4 + j;
        float v = (acc[ct][j] + qb[col]) * (0.0625f * 1.4426950408889634f);
        Qs[(size_t)row * CDIM + col] = f2bf(v);
      }
    }
  } else if (b < 272) {
    int m0 = (b - 128) * 64;
    const unsigned short* abase = stn + (size_t)(m0 + w * 16 + li) * CDIM + g * 8;
    #pragma unroll
    for (int kc = 0; kc < 8; kc++) {
      short8 a = *(const short8*)(abase + kc * 32);
      #pragma unroll
      for (int ct = 0; ct < 16; ct++) {
        short8 bb = *(const short8*)(kwb + (size_t)(ct * 16 + li) * CDIM + kc * 32 + g * 8);
        acc[ct] = __builtin_amdgcn_mfma_f32_16x16x32_bf16(a, bb, acc[ct], 0, 0, 0);
      }
    }
    #pragma unroll
    for (int ct = 0; ct < 16; ct++) {
      int col = ct * 16 + li;
      #pragma unroll
      for (int j = 0; j < 4; j++) {
        int row = m0 + w * 16 + g * 4 + j;
        Km[(size_t)row * CDIM + col] = f2bf(acc[ct][j] + kb[col]);
      }
    }
  } else {
    int bb2 = b - 272;
    int m0 = (bb2 & 3) * 64, n0 = (bb2 >> 2) * 256;
    const unsigned short* abase = swb + (size_t)(m0 + w * 16 + li) * CDIM + g * 8;
    #pragma unroll
    for (int kc = 0; kc < 8; kc++) {
      short8 a = *(const short8*)(abase + kc * 32);
      #pragma unroll
      for (int ct = 0; ct < 16; ct++) {
        short8 bb = *(const short8*)(stT + (size_t)(n0 + ct * 16 + li) * CDIM + kc * 32 + g * 8);
        acc[ct] = __builtin_amdgcn_mfma_f32_16x16x32_bf16(a, bb, acc[ct], 0, 0, 0);
      }
    }
    #pragma unroll
    for (int ct = 0; ct < 16; ct++) {
      int col = n0 + ct * 16 + li;
      #pragma unroll
      for (int j = 0; j < 4; j++) {
        int row = m0 + w * 16 + g * 4 + j;
        float v = acc[ct][j] + sbf[row];
        VseT[(size_t)row * HWN + col] = f2bf(v);
        Vse2T[(size_t)row * HWN + col] = f2bf(v * v);
      }
    }
  }
}

// ---------------- split-K flash attention (round-7 structure, verbatim; THR=8) ----------------
static __device__ __forceinline__ void issue_K(int p0, int w, int lane,
                                               const unsigned short* __restrict__ Km,
                                               unsigned short* K_buf) {
  #pragma unroll
  for (int j2 = 0; j2 < 2; j2++) {
    int i16 = (j2 * 8 + w) * 64 + lane;
    int row = i16 >> 5;
    int chc = (i16 & 31) ^ (row & 15);
    const unsigned short* src = Km + (size_t)(p0 + row) * CDIM + chc * 8;
    unsigned short* dst = K_buf + (j2 * 8 + w) * 512;
    __builtin_amdgcn_global_load_lds((const __attribute__((address_space(1))) unsigned int*)src,
                                     (__attribute__((address_space(3))) unsigned int*)dst, 16, 0, 0);
  }
}

static __device__ __forceinline__ void issue_V(int p0, int w, int lane,
                                               const unsigned short* __restrict__ VseT,
                                               const unsigned short* __restrict__ Vse2T,
                                               unsigned short* V_buf) {
  #pragma unroll
  for (int j2 = 0; j2 < 4; j2++) {
    int i16 = (j2 * 8 + w) * 64 + lane;
    int vrow = i16 >> 2;
    int chunk = (i16 & 3) ^ ((vrow >> 1) & 3);
    const unsigned short* src = (vrow < 256 ? VseT + (size_t)vrow * HWN
                                            : Vse2T + (size_t)(vrow - 256) * HWN) + p0 + chunk * 8;
    unsigned short* dst = V_buf + (j2 * 8 + w) * 512;
    __builtin_amdgcn_global_load_lds((const __attribute__((address_space(1))) unsigned int*)src,
                                     (__attribute__((address_space(3))) unsigned int*)dst, 16, 0, 0);
  }
}

__global__ __launch_bounds__(512, 1) void attn_kernel(const unsigned short* __restrict__ Qs,
                                                      const unsigned short* __restrict__ Km,
                                                      const unsigned short* __restrict__ VseT,
                                                      const unsigned short* __restrict__ Vse2T,
                                                      float* __restrict__ Op, float2* __restrict__ ml,
                                                      int tiles_per_g, int G) {
  __shared__ __align__(16) unsigned short K_lds[2][32 * 256];   // 16KB x2
  __shared__ __align__(16) unsigned short V_lds[3][512 * 32];   // 32KB x3
  __shared__ __align__(16) unsigned short P_lds[2][128 * 40];   // 10KB x2
  __shared__ float corr_lds[128];
  __shared__ int needflag[8];

  const int t = threadIdx.x;
  const int w = t >> 6, lane = t & 63;
  const int g4 = lane >> 4, li = lane & 15;

  int bid = blockIdx.x, qb, g;
  if (G == 4) { g = (bid & 7) >> 1; qb = ((bid & 1) << 5) + (bid >> 3); }
  else        { g = bid % G;        qb = bid / G; }
  const int n0 = qb * 128;
  const int p_begin = g * tiles_per_g * 32;

  short8 qf[8];
  {
    const unsigned short* qbase = Qs + (size_t)(n0 + w * 16 + li) * CDIM + g4 * 8;
    #pragma unroll
    for (int kc = 0; kc < 8; kc++) qf[kc] = *(const short8*)(qbase + kc * 32);
  }
  float4v O[8][4];
  #pragma unroll
  for (int r = 0; r < 8; r++)
    #pragma unroll
    for (int v = 0; v < 4; v++) O[r][v] = (float4v){0.f, 0.f, 0.f, 0.f};
  float4v s_acc = (float4v){0.f, 0.f, 0.f, 0.f};
  float m[4] = {-1e30f, -1e30f, -1e30f, -1e30f};
  const short8 ones = (short8){0x3F80, 0x3F80, 0x3F80, 0x3F80, 0x3F80, 0x3F80, 0x3F80, 0x3F80};

#define PV_BLOCK(P_buf, V_buf)                                                               \
  {                                                                                          \
    short8 vb[4];                                                                            \
    _Pragma("unroll")                                                                        \
    for (int v = 0; v < 4; v++) {                                                            \
      int vrow = w * 64 + v * 16 + li;                                                       \
      vb[v] = *(const short8*)((const char*)(V_buf) + vrow * 64 + ((g4 ^ ((vrow >> 1) & 3)) << 4)); \
    }                                                                                        \
    __builtin_amdgcn_s_setprio(1);                                                           \
    _Pragma("unroll")                                                                        \
    for (int r = 0; r < 8; r++) {                                                            \
      short8 pa = *(const short8*)((P_buf) + (r * 16 + li) * 40 + g4 * 8);                   \
      if (r == w) s_acc = __builtin_amdgcn_mfma_f32_16x16x32_bf16(pa, ones, s_acc, 0, 0, 0); \
      _Pragma("unroll")                                                                      \
      for (int v = 0; v < 4; v++)                                                            \
        O[r][v] = __builtin_amdgcn_mfma_f32_16x16x32_bf16(pa, vb[v], O[r][v], 0, 0, 0);      \
    }                                                                                        \
    __builtin_amdgcn_s_setprio(0);                                                           \
  }

  issue_K(p_begin, w, lane, Km, K_lds[0]);
  issue_V(p_begin, w, lane, VseT, Vse2T, V_lds[0]);

  for (int it = 0; it < tiles_per_g; ++it) {
    if (it + 1 < tiles_per_g) {
      issue_K(p_begin + (it + 1) * 32, w, lane, Km, K_lds[(it + 1) & 1]);
      issue_V(p_begin + (it + 1) * 32, w, lane, VseT, Vse2T, V_lds[(it + 1) % 3]);
      asm volatile("s_waitcnt vmcnt(6)" ::: "memory");
    } else {
      asm volatile("s_waitcnt vmcnt(0)" ::: "memory");
    }
    __builtin_amdgcn_s_barrier();              // TOP: tile t staged; iter t-1 consumers done
    asm volatile("" ::: "memory");

    // --- QK(t) ---
    const unsigned short* Kc = K_lds[it & 1];
    float4v S0 = (float4v){0.f, 0.f, 0.f, 0.f}, S1 = (float4v){0.f, 0.f, 0.f, 0.f};
    __builtin_amdgcn_s_setprio(1);
    #pragma unroll
    for (int kc = 0; kc < 8; kc++) {
      int c = kc * 4 + g4;
      short8 b0 = *(const short8*)((const char*)Kc + li * 512 + ((c ^ li) << 4));
      short8 b1 = *(const short8*)((const char*)Kc + (16 + li) * 512 + ((c ^ li) << 4));
      S0 = __builtin_amdgcn_mfma_f32_16x16x32_bf16(qf[kc], b0, S0, 0, 0, 0);
      S1 = __builtin_amdgcn_mfma_f32_16x16x32_bf16(qf[kc], b1, S1, 0, 0, 0);
    }
    __builtin_amdgcn_s_setprio(0);

    // --- PV(t-1): overlaps softmax(t) ---
    if (it > 0) PV_BLOCK(P_lds[(it - 1) & 1], V_lds[(it - 1) % 3]);

    // --- softmax(t) (defer-max THR=8 in log2 units) ---
    float pmax[4], corr[4];
    #pragma unroll
    for (int j = 0; j < 4; j++) {
      float mx = fmaxf(S0[j], S1[j]);
      #pragma unroll
      for (int msk = 1; msk < 16; msk <<= 1) mx = fmaxf(mx, __shfl_xor(mx, msk, 64));
      pmax[j] = mx;
    }
    int needs = ((pmax[0] > m[0] + 8.f) || (pmax[1] > m[1] + 8.f) ||
                 (pmax[2] > m[2] + 8.f) || (pmax[3] > m[3] + 8.f)) ? 1 : 0;
    if (needs) {
      #pragma unroll
      for (int j = 0; j < 4; j++) {
        float mn = fmaxf(m[j], pmax[j]);
        corr[j] = exp2f(m[j] - mn);
        m[j] = mn;
      }
    } else {
      corr[0] = corr[1] = corr[2] = corr[3] = 1.f;
    }
    int wany = __any(needs) ? 1 : 0;
    unsigned short* Pw = P_lds[it & 1];
    #pragma unroll
    for (int j = 0; j < 4; j++) {
      float e0 = exp2f(S0[j] - m[j]);
      float e1 = exp2f(S1[j] - m[j]);
      int row = w * 16 + g4 * 4 + j;
      Pw[row * 40 + li] = f2bf(e0);
      Pw[row * 40 + 16 + li] = f2bf(e1);
      if (li == 0) corr_lds[row] = corr[j];
    }
    if (lane == 0) needflag[w] = wany;

    asm volatile("s_waitcnt lgkmcnt(0)" ::: "memory");
    __builtin_amdgcn_s_barrier();              // MID: P(t)/corr/flags visible
    asm volatile("" ::: "memory");

    // --- phase 2: rescale O by corr(t) ---
    int any = __any(needflag[lane & 7] != 0);
    if (any) {
      #pragma unroll
      for (int j = 0; j < 4; j++) s_acc[j] *= corr[j];
      #pragma unroll
      for (int r = 0; r < 8; r++) {
        float c0 = corr_lds[r * 16 + g4 * 4 + 0];
        float c1 = corr_lds[r * 16 + g4 * 4 + 1];
        float c2 = corr_lds[r * 16 + g4 * 4 + 2];
        float c3 = corr_lds[r * 16 + g4 * 4 + 3];
        #pragma unroll
        for (int v = 0; v < 4; v++) {
          O[r][v][0] *= c0; O[r][v][1] *= c1; O[r][v][2] *= c2; O[r][v][3] *= c3;
        }
      }
    }
  }

  // drain: PV for the last tile
  {
    int tl = tiles_per_g - 1;
    PV_BLOCK(P_lds[tl & 1], V_lds[tl % 3]);
  }
#undef PV_BLOCK

  // write partials
  #pragma unroll
  for (int r = 0; r < 8; r++) {
    #pragma unroll
    for (int v = 0; v < 4; v++) {
      #pragma unroll
      for (int j = 0; j < 4; j++) {
        int n = n0 + r * 16 + g4 * 4 + j;
        int vd = w * 64 + v * 16 + li;
        Op[((size_t)g * NQ + n) * 512 + vd] = O[r][v][j];
      }
    }
  }
  if (li == 0) {
    #pragma unroll
    for (int j = 0; j < 4; j++) {
      int n = n0 + w * 16 + g4 * 4 + j;
      ml[(size_t)g * NQ + n] = make_float2(m[j], s_acc[j]);
    }
  }
}

// ---------------- combine (float4) + AdaAttN epilogue (exp2 domain) ----------------
__global__ __launch_bounds__(256) void combine_kernel(const float* __restrict__ Op, const float2* __restrict__ ml,
                                                      const float* __restrict__ q,
                                                      const float* __restrict__ mq, const float* __restrict__ rq,
                                                      float* __restrict__ out, int G) {
  int t = threadIdx.x;
  int rl = t >> 6, j = t & 63;
  int n = blockIdx.x * 4 + rl, c0 = j * 4;
  __shared__ float wsm[4][8];
  if (j == 0) {
    float mstar = -1e30f;
    float mg[8], lg[8];
    for (int g = 0; g < G; g++) {
      float2 v = ml[(size_t)g * NQ + n];
      mg[g] = v.x; lg[g] = v.y;
      mstar = fmaxf(mstar, v.x);
    }
    float L = 0.f;
    for (int g = 0; g < G; g++) L += lg[g] * exp2f(mg[g] - mstar);
    float Li = 1.f / L;
    for (int g = 0; g < G; g++) wsm[rl][g] = exp2f(mg[g] - mstar) * Li;
  }
  __syncthreads();
  float4 of = make_float4(0, 0, 0, 0), o2 = make_float4(0, 0, 0, 0);
  for (int g = 0; g < G; g++) {
    size_t base = ((size_t)g * NQ + n) * 512;
    float wg = wsm[rl][g];
    float4 a = *(const float4*)(Op + base + c0);
    float4 b = *(const float4*)(Op + base + 256 + c0);
    of.x += wg * a.x; of.y += wg * a.y; of.z += wg * a.z; of.w += wg * a.w;
    o2.x += wg * b.x; o2.y += wg * b.y; o2.z += wg * b.z; o2.w += wg * b.w;
  }
  float4 qv = *(const float4*)(q + (size_t)n * CDIM + c0);
  float4 mv = *(const float4*)(mq + c0);
  float4 rv = *(const float4*)(rq + c0);
  float4 ov;
  ov.x = (qv.x - mv.x) * rv.x * sqrtf(fmaxf(o2.x - of.x * of.x, 0.f)) + of.x;
  ov.y = (qv.y - mv.y) * rv.y * sqrtf(fmaxf(o2.y - of.y * of.y, 0.f)) + of.y;
  ov.z = (qv.z - mv.z) * rv.z * sqrtf(fmaxf(o2.z - of.z * of.z, 0.f)) + of.z;
  ov.w = (qv.w - mv.w) * rv.w * sqrtf(fmaxf(o2.w - of.w * of.w, 0.f)) + of.w;
  *(float4*)(out + (size_t)n * CDIM + c0) = ov;
}

extern "C" void kernel_launch(void* const* d_in, const int* in_sizes, int n_in,
                              void* d_out, int out_size, void* d_ws, size_t ws_size,
                              hipStream_t stream) {
  const float* q  = (const float*)d_in[0];
  const float* k0 = (const float*)d_in[1];
  const float* qw = (const float*)d_in[2];
  const float* qb = (const float*)d_in[3];
  const float* kw = (const float*)d_in[4];
  const float* kb = (const float*)d_in[5];
  const float* sw = (const float*)d_in[6];
  const float* sb = (const float*)d_in[7];
  float* out = (float*)d_out;

  char* ws = (char*)d_ws;
  float* mq   = (float*)ws; ws += 1024;
  float* rq   = (float*)ws; ws += 1024;
  float* mk   = (float*)ws; ws += 1024;
  float* rk   = (float*)ws; ws += 1024;
  float* pq   = (float*)ws; ws += 256 * 256 * 4;
  float* pq2  = (float*)ws; ws += 256 * 256 * 4;
  unsigned short* qwb = (unsigned short*)ws; ws += 65536 * 2;
  unsigned short* kwb = (unsigned short*)ws; ws += 65536 * 2;
  unsigned short* swb = (unsigned short*)ws; ws += 65536 * 2;
  unsigned short* Qs    = (unsigned short*)ws; ws += (size_t)NQ * CDIM * 2;
  unsigned short* stn   = (unsigned short*)ws; ws += (size_t)HWN * CDIM * 2;
  unsigned short* Km    = (unsigned short*)ws; ws += (size_t)HWN * CDIM * 2;
  unsigned short* VseT  = (unsigned short*)ws; ws += (size_t)HWN * CDIM * 2;
  unsigned short* Vse2T = (unsigned short*)ws; ws += (size_t)HWN * CDIM * 2;

  // stT carved from the workspace TAIL: dead before attn writes Op there (order-safe).
  unsigned short* stT = (unsigned short*)((char*)d_ws +
                          ((ws_size - (size_t)HWN * CDIM * 2) & ~(size_t)15));

  size_t base_used = (size_t)(ws - (char*)d_ws);
  int G = 4;
  const int gcand[3] = {4, 2, 1};
  for (int i = 0; i < 3; i++) {
    G = gcand[i];
    size_t need = base_used + (size_t)G * ((size_t)NQ * 512 * 4 + (size_t)NQ * 8);
    if (need <= ws_size) break;
  }
  float*  Opart = (float*)ws;                 ws += (size_t)G * NQ * 512 * 4;
  float2* mlp   = (float2*)ws;                ws += (size_t)G * NQ * 8;
  int tiles_per_g = (HWN / 32) / G;

  stats_all_kernel<<<512, 256, 0, stream>>>(q, k0, pq, pq2, mk, rk);
  cvtall_kernel<<<193, 256, 0, stream>>>(qw, kw, sw, qwb, kwb, swb, pq, pq2, mq, rq);
  ktrans_kernel<<<dim3(HWN / 32, CDIM / 32), 256, 0, stream>>>(k0, mk, rk, stT, stn);
  gemms_kernel<<<416, 256, 0, stream>>>(q, mq, rq, qwb, qb, Qs, stn, kwb, kb, Km, swb, sb, stT, VseT, Vse2T);
  attn_kernel<<<dim3(64 * G), 512, 0, stream>>>(Qs, Km, VseT, Vse2T, Opart, mlp, tiles_per_g, G);
  combine_kernel<<<NQ / 4, 256, 0, stream>>>(Opart, mlp, q, mq, rq, out, G);
}

// Round 14
// 282.561 us; speedup vs baseline: 1.0786x; 1.0156x over previous
//
#include <hip/hip_runtime.h>

typedef __attribute__((ext_vector_type(8))) short short8;
typedef __attribute__((ext_vector_type(4))) float float4v;

#define CDIM 256
#define NQ   8192
#define HWN  9216

static __device__ __forceinline__ unsigned short f2bf(float f) {
  union { float f; unsigned int i; } v; v.f = f;
  unsigned int r = v.i + 0x7FFFu + ((v.i >> 16) & 1u);
  return (unsigned short)(r >> 16);
}

// ---------------- fused stats: blocks 0-255 q-partials, 256-511 k-channels ----------------
__global__ __launch_bounds__(256) void stats_all_kernel(const float* __restrict__ q, const float* __restrict__ k0,
                                                        float* __restrict__ pq, float* __restrict__ pq2,
                                                        float* __restrict__ mk, float* __restrict__ rk) {
  int b = blockIdx.x, t = threadIdx.x;
  if (b < 256) {
    const float4* q4 = (const float4*)(q + (size_t)b * 32 * CDIM);
    float sx = 0, sy = 0, sz = 0, sw = 0, tx = 0, ty = 0, tz = 0, tw = 0;
    for (int i = t; i < 32 * 64; i += 256) {
      float4 v = q4[i];
      sx += v.x; sy += v.y; sz += v.z; sw += v.w;
      tx += v.x * v.x; ty += v.y * v.y; tz += v.z * v.z; tw += v.w * v.w;
    }
    __shared__ float4 sA[256], sB[256];
    sA[t] = make_float4(sx, sy, sz, sw); sB[t] = make_float4(tx, ty, tz, tw);
    __syncthreads();
    if (t < 64) {
      float4 a = sA[t], b2 = sB[t];
      #pragma unroll
      for (int r = 1; r < 4; r++) {
        float4 u = sA[t + r * 64], w2 = sB[t + r * 64];
        a.x += u.x; a.y += u.y; a.z += u.z; a.w += u.w;
        b2.x += w2.x; b2.y += w2.y; b2.z += w2.z; b2.w += w2.w;
      }
      ((float4*)pq)[b * 64 + t] = a;
      ((float4*)pq2)[b * 64 + t] = b2;
    }
  } else {
    __shared__ float rs[256], rs2[256];
    int c = b - 256;
    float s = 0.f, s2 = 0.f;
    const float4* row = (const float4*)(k0 + (size_t)c * HWN);
    for (int j = t; j < HWN / 4; j += 256) {
      float4 v = row[j];
      s += v.x + v.y + v.z + v.w;
      s2 += v.x * v.x + v.y * v.y + v.z * v.z + v.w * v.w;
    }
    rs[t] = s; rs2[t] = s2; __syncthreads();
    for (int off = 128; off > 0; off >>= 1) {
      if (t < off) { rs[t] += rs[t + off]; rs2[t] += rs2[t + off]; }
      __syncthreads();
    }
    if (t == 0) {
      float mean = rs[0] / (float)HWN;
      float var = fmaxf(rs2[0] / (float)HWN - mean * mean, 0.f);
      mk[c] = mean; rk[c] = rsqrtf(var + 1e-5f);
    }
  }
}

// ---------------- cvts (plain, unfolded) + q-stats finalize ----------------
__global__ __launch_bounds__(256) void cvtall_kernel(const float* __restrict__ qw, const float* __restrict__ kw,
                                                     const float* __restrict__ sw,
                                                     unsigned short* __restrict__ qwb, unsigned short* __restrict__ kwb,
                                                     unsigned short* __restrict__ swb,
                                                     const float* __restrict__ pq, const float* __restrict__ pq2,
                                                     float* __restrict__ mq, float* __restrict__ rq) {
  int b = blockIdx.x, t = threadIdx.x;
  if (b < 192) {
    const float* src = b < 64 ? qw : (b < 128 ? kw : sw);
    unsigned short* dst = b < 64 ? qwb : (b < 128 ? kwb : swb);
    int i = (b & 63) * 256 + t;
    float4 v = ((const float4*)src)[i];
    union { unsigned short o[4]; uint2 u; } w;
    w.o[0] = f2bf(v.x); w.o[1] = f2bf(v.y); w.o[2] = f2bf(v.z); w.o[3] = f2bf(v.w);
    ((uint2*)dst)[i] = w.u;
  } else {
    int c = t;
    float s = 0, s2 = 0;
    for (int bb = 0; bb < 256; bb++) { s += pq[bb * 256 + c]; s2 += pq2[bb * 256 + c]; }
    float mean = s / (float)NQ;
    float var = s2 / (float)NQ - mean * mean;
    mq[c] = mean; rq[c] = rsqrtf(fmaxf(var, 0.f) + 1e-5f);
  }
}

// ---------------- transpose k (C,HW) f32 -> stT (HW,C) bf16 raw + stn normalized ----------------
__global__ __launch_bounds__(256) void ktrans_kernel(const float* __restrict__ k0,
                                                     const float* __restrict__ mk, const float* __restrict__ rk,
                                                     unsigned short* __restrict__ stT, unsigned short* __restrict__ stn) {
  __shared__ float tile[32][33];
  int p0 = blockIdx.x * 32, c0 = blockIdx.y * 32;
  int t = threadIdx.x;
  int pl = t & 31, cl = t >> 5;
  #pragma unroll
  for (int r = 0; r < 4; r++) {
    int c = cl + r * 8;
    tile[c][pl] = k0[(size_t)(c0 + c) * HWN + p0 + pl];
  }
  __syncthreads();
  int cl2 = t & 31, pl2 = t >> 5;
  float mean = mk[c0 + cl2], rinv = rk[c0 + cl2];
  #pragma unroll
  for (int r = 0; r < 4; r++) {
    int p = pl2 + r * 8;
    float f = tile[cl2][p];
    stT[(size_t)(p0 + p) * CDIM + c0 + cl2] = f2bf(f);
    stn[(size_t)(p0 + p) * CDIM + c0 + cl2] = f2bf((f - mean) * rinv);
  }
}

// ---------------- mega-GEMM: logical blocks [0,128) Qs; [128,272) Km; [272,416) se/se^2 ----------------
// blockIdx remapped XCD-bijectively (416 = 8*52): placement-only change, outputs bitwise identical.
__global__ __launch_bounds__(256) void gemms_kernel(const float* __restrict__ qf,
                                                    const float* __restrict__ mq, const float* __restrict__ rq,
                                                    const unsigned short* __restrict__ qwb, const float* __restrict__ qb,
                                                    unsigned short* __restrict__ Qs,
                                                    const unsigned short* __restrict__ stn,
                                                    const unsigned short* __restrict__ kwb, const float* __restrict__ kb,
                                                    unsigned short* __restrict__ Km,
                                                    const unsigned short* __restrict__ swb, const float* __restrict__ sbf,
                                                    const unsigned short* __restrict__ stT,
                                                    unsigned short* __restrict__ VseT, unsigned short* __restrict__ Vse2T) {
  int bid = blockIdx.x, t = threadIdx.x;
  int b = (bid & 7) * 52 + (bid >> 3);   // bijective: bid in [0,416) -> b in [0,416)
  int w = t >> 6, lane = t & 63, g = lane >> 4, li = lane & 15;
  float4v acc[16];
  #pragma unroll
  for (int i = 0; i < 16; i++) acc[i] = (float4v){0.f, 0.f, 0.f, 0.f};

  if (b < 128) {
    int m0 = b * 64;
    const float* abase = qf + (size_t)(m0 + w * 16 + li) * CDIM + g * 8;
    #pragma unroll
    for (int kc = 0; kc < 8; kc++) {
      int c0 = kc * 32 + g * 8;
      float4 f0 = *(const float4*)(abase + kc * 32);
      float4 f1 = *(const float4*)(abase + kc * 32 + 4);
      float4 m0v = *(const float4*)(mq + c0), m1v = *(const float4*)(mq + c0 + 4);
      float4 r0v = *(const float4*)(rq + c0), r1v = *(const float4*)(rq + c0 + 4);
      union { unsigned short o[8]; short8 s; } a;
      a.o[0] = f2bf((f0.x - m0v.x) * r0v.x); a.o[1] = f2bf((f0.y - m0v.y) * r0v.y);
      a.o[2] = f2bf((f0.z - m0v.z) * r0v.z); a.o[3] = f2bf((f0.w - m0v.w) * r0v.w);
      a.o[4] = f2bf((f1.x - m1v.x) * r1v.x); a.o[5] = f2bf((f1.y - m1v.y) * r1v.y);
      a.o[6] = f2bf((f1.z - m1v.z) * r1v.z); a.o[7] = f2bf((f1.w - m1v.w) * r1v.w);
      #pragma unroll
      for (int ct = 0; ct < 16; ct++) {
        short8 bb = *(const short8*)(qwb + (size_t)(ct * 16 + li) * CDIM + kc * 32 + g * 8);
        acc[ct] = __builtin_amdgcn_mfma_f32_16x16x32_bf16(a.s, bb, acc[ct], 0, 0, 0);
      }
    }
    #pragma unroll
    for (int ct = 0; ct < 16; ct++) {
      int col = ct * 16 + li;
      #pragma unroll
      for (int j = 0; j < 4; j++) {
        int row = m0 + w * 16 + g * 4 + j;
        float v = (acc[ct][j] + qb[col]) * (0.0625f * 1.4426950408889634f);
        Qs[(size_t)row * CDIM + col] = f2bf(v);
      }
    }
  } else if (b < 272) {
    int m0 = (b - 128) * 64;
    const unsigned short* abase = stn + (size_t)(m0 + w * 16 + li) * CDIM + g * 8;
    #pragma unroll
    for (int kc = 0; kc < 8; kc++) {
      short8 a = *(const short8*)(abase + kc * 32);
      #pragma unroll
      for (int ct = 0; ct < 16; ct++) {
        short8 bb = *(const short8*)(kwb + (size_t)(ct * 16 + li) * CDIM + kc * 32 + g * 8);
        acc[ct] = __builtin_amdgcn_mfma_f32_16x16x32_bf16(a, bb, acc[ct], 0, 0, 0);
      }
    }
    #pragma unroll
    for (int ct = 0; ct < 16; ct++) {
      int col = ct * 16 + li;
      #pragma unroll
      for (int j = 0; j < 4; j++) {
        int row = m0 + w * 16 + g * 4 + j;
        Km[(size_t)row * CDIM + col] = f2bf(acc[ct][j] + kb[col]);
      }
    }
  } else {
    int bb2 = b - 272;
    int m0 = (bb2 & 3) * 64, n0 = (bb2 >> 2) * 256;
    const unsigned short* abase = swb + (size_t)(m0 + w * 16 + li) * CDIM + g * 8;
    #pragma unroll
    for (int kc = 0; kc < 8; kc++) {
      short8 a = *(const short8*)(abase + kc * 32);
      #pragma unroll
      for (int ct = 0; ct < 16; ct++) {
        short8 bb = *(const short8*)(stT + (size_t)(n0 + ct * 16 + li) * CDIM + kc * 32 + g * 8);
        acc[ct] = __builtin_amdgcn_mfma_f32_16x16x32_bf16(a, bb, acc[ct], 0, 0, 0);
      }
    }
    #pragma unroll
    for (int ct = 0; ct < 16; ct++) {
      int col = n0 + ct * 16 + li;
      #pragma unroll
      for (int j = 0; j < 4; j++) {
        int row = m0 + w * 16 + g * 4 + j;
        float v = acc[ct][j] + sbf[row];
        VseT[(size_t)row * HWN + col] = f2bf(v);
        Vse2T[(size_t)row * HWN + col] = f2bf(v * v);
      }
    }
  }
}

// ---------------- split-K flash attention (round-7 structure, verbatim; THR=8) ----------------
static __device__ __forceinline__ void issue_K(int p0, int w, int lane,
                                               const unsigned short* __restrict__ Km,
                                               unsigned short* K_buf) {
  #pragma unroll
  for (int j2 = 0; j2 < 2; j2++) {
    int i16 = (j2 * 8 + w) * 64 + lane;
    int row = i16 >> 5;
    int chc = (i16 & 31) ^ (row & 15);
    const unsigned short* src = Km + (size_t)(p0 + row) * CDIM + chc * 8;
    unsigned short* dst = K_buf + (j2 * 8 + w) * 512;
    __builtin_amdgcn_global_load_lds((const __attribute__((address_space(1))) unsigned int*)src,
                                     (__attribute__((address_space(3))) unsigned int*)dst, 16, 0, 0);
  }
}

static __device__ __forceinline__ void issue_V(int p0, int w, int lane,
                                               const unsigned short* __restrict__ VseT,
                                               const unsigned short* __restrict__ Vse2T,
                                               unsigned short* V_buf) {
  #pragma unroll
  for (int j2 = 0; j2 < 4; j2++) {
    int i16 = (j2 * 8 + w) * 64 + lane;
    int vrow = i16 >> 2;
    int chunk = (i16 & 3) ^ ((vrow >> 1) & 3);
    const unsigned short* src = (vrow < 256 ? VseT + (size_t)vrow * HWN
                                            : Vse2T + (size_t)(vrow - 256) * HWN) + p0 + chunk * 8;
    unsigned short* dst = V_buf + (j2 * 8 + w) * 512;
    __builtin_amdgcn_global_load_lds((const __attribute__((address_space(1))) unsigned int*)src,
                                     (__attribute__((address_space(3))) unsigned int*)dst, 16, 0, 0);
  }
}

__global__ __launch_bounds__(512, 1) void attn_kernel(const unsigned short* __restrict__ Qs,
                                                      const unsigned short* __restrict__ Km,
                                                      const unsigned short* __restrict__ VseT,
                                                      const unsigned short* __restrict__ Vse2T,
                                                      float* __restrict__ Op, float2* __restrict__ ml,
                                                      int tiles_per_g, int G) {
  __shared__ __align__(16) unsigned short K_lds[2][32 * 256];   // 16KB x2
  __shared__ __align__(16) unsigned short V_lds[3][512 * 32];   // 32KB x3
  __shared__ __align__(16) unsigned short P_lds[2][128 * 40];   // 10KB x2
  __shared__ float corr_lds[128];
  __shared__ int needflag[8];

  const int t = threadIdx.x;
  const int w = t >> 6, lane = t & 63;
  const int g4 = lane >> 4, li = lane & 15;

  int bid = blockIdx.x, qb, g;
  if (G == 4) { g = (bid & 7) >> 1; qb = ((bid & 1) << 5) + (bid >> 3); }
  else        { g = bid % G;        qb = bid / G; }
  const int n0 = qb * 128;
  const int p_begin = g * tiles_per_g * 32;

  short8 qf[8];
  {
    const unsigned short* qbase = Qs + (size_t)(n0 + w * 16 + li) * CDIM + g4 * 8;
    #pragma unroll
    for (int kc = 0; kc < 8; kc++) qf[kc] = *(const short8*)(qbase + kc * 32);
  }
  float4v O[8][4];
  #pragma unroll
  for (int r = 0; r < 8; r++)
    #pragma unroll
    for (int v = 0; v < 4; v++) O[r][v] = (float4v){0.f, 0.f, 0.f, 0.f};
  float4v s_acc = (float4v){0.f, 0.f, 0.f, 0.f};
  float m[4] = {-1e30f, -1e30f, -1e30f, -1e30f};
  const short8 ones = (short8){0x3F80, 0x3F80, 0x3F80, 0x3F80, 0x3F80, 0x3F80, 0x3F80, 0x3F80};

#define PV_BLOCK(P_buf, V_buf)                                                               \
  {                                                                                          \
    short8 vb[4];                                                                            \
    _Pragma("unroll")                                                                        \
    for (int v = 0; v < 4; v++) {                                                            \
      int vrow = w * 64 + v * 16 + li;                                                       \
      vb[v] = *(const short8*)((const char*)(V_buf) + vrow * 64 + ((g4 ^ ((vrow >> 1) & 3)) << 4)); \
    }                                                                                        \
    __builtin_amdgcn_s_setprio(1);                                                           \
    _Pragma("unroll")                                                                        \
    for (int r = 0; r < 8; r++) {                                                            \
      short8 pa = *(const short8*)((P_buf) + (r * 16 + li) * 40 + g4 * 8);                   \
      if (r == w) s_acc = __builtin_amdgcn_mfma_f32_16x16x32_bf16(pa, ones, s_acc, 0, 0, 0); \
      _Pragma("unroll")                                                                      \
      for (int v = 0; v < 4; v++)                                                            \
        O[r][v] = __builtin_amdgcn_mfma_f32_16x16x32_bf16(pa, vb[v], O[r][v], 0, 0, 0);      \
    }                                                                                        \
    __builtin_amdgcn_s_setprio(0);                                                           \
  }

  issue_K(p_begin, w, lane, Km, K_lds[0]);
  issue_V(p_begin, w, lane, VseT, Vse2T, V_lds[0]);

  for (int it = 0; it < tiles_per_g; ++it) {
    if (it + 1 < tiles_per_g) {
      issue_K(p_begin + (it + 1) * 32, w, lane, Km, K_lds[(it + 1) & 1]);
      issue_V(p_begin + (it + 1) * 32, w, lane, VseT, Vse2T, V_lds[(it + 1) % 3]);
      asm volatile("s_waitcnt vmcnt(6)" ::: "memory");
    } else {
      asm volatile("s_waitcnt vmcnt(0)" ::: "memory");
    }
    __builtin_amdgcn_s_barrier();              // TOP: tile t staged; iter t-1 consumers done
    asm volatile("" ::: "memory");

    // --- QK(t) ---
    const unsigned short* Kc = K_lds[it & 1];
    float4v S0 = (float4v){0.f, 0.f, 0.f, 0.f}, S1 = (float4v){0.f, 0.f, 0.f, 0.f};
    __builtin_amdgcn_s_setprio(1);
    #pragma unroll
    for (int kc = 0; kc < 8; kc++) {
      int c = kc * 4 + g4;
      short8 b0 = *(const short8*)((const char*)Kc + li * 512 + ((c ^ li) << 4));
      short8 b1 = *(const short8*)((const char*)Kc + (16 + li) * 512 + ((c ^ li) << 4));
      S0 = __builtin_amdgcn_mfma_f32_16x16x32_bf16(qf[kc], b0, S0, 0, 0, 0);
      S1 = __builtin_amdgcn_mfma_f32_16x16x32_bf16(qf[kc], b1, S1, 0, 0, 0);
    }
    __builtin_amdgcn_s_setprio(0);

    // --- PV(t-1): overlaps softmax(t) ---
    if (it > 0) PV_BLOCK(P_lds[(it - 1) & 1], V_lds[(it - 1) % 3]);

    // --- softmax(t) (defer-max THR=8 in log2 units) ---
    float pmax[4], corr[4];
    #pragma unroll
    for (int j = 0; j < 4; j++) {
      float mx = fmaxf(S0[j], S1[j]);
      #pragma unroll
      for (int msk = 1; msk < 16; msk <<= 1) mx = fmaxf(mx, __shfl_xor(mx, msk, 64));
      pmax[j] = mx;
    }
    int needs = ((pmax[0] > m[0] + 8.f) || (pmax[1] > m[1] + 8.f) ||
                 (pmax[2] > m[2] + 8.f) || (pmax[3] > m[3] + 8.f)) ? 1 : 0;
    if (needs) {
      #pragma unroll
      for (int j = 0; j < 4; j++) {
        float mn = fmaxf(m[j], pmax[j]);
        corr[j] = exp2f(m[j] - mn);
        m[j] = mn;
      }
    } else {
      corr[0] = corr[1] = corr[2] = corr[3] = 1.f;
    }
    int wany = __any(needs) ? 1 : 0;
    unsigned short* Pw = P_lds[it & 1];
    #pragma unroll
    for (int j = 0; j < 4; j++) {
      float e0 = exp2f(S0[j] - m[j]);
      float e1 = exp2f(S1[j] - m[j]);
      int row = w * 16 + g4 * 4 + j;
      Pw[row * 40 + li] = f2bf(e0);
      Pw[row * 40 + 16 + li] = f2bf(e1);
      if (li == 0) corr_lds[row] = corr[j];
    }
    if (lane == 0) needflag[w] = wany;

    asm volatile("s_waitcnt lgkmcnt(0)" ::: "memory");
    __builtin_amdgcn_s_barrier();              // MID: P(t)/corr/flags visible
    asm volatile("" ::: "memory");

    // --- phase 2: rescale O by corr(t) ---
    int any = __any(needflag[lane & 7] != 0);
    if (any) {
      #pragma unroll
      for (int j = 0; j < 4; j++) s_acc[j] *= corr[j];
      #pragma unroll
      for (int r = 0; r < 8; r++) {
        float c0 = corr_lds[r * 16 + g4 * 4 + 0];
        float c1 = corr_lds[r * 16 + g4 * 4 + 1];
        float c2 = corr_lds[r * 16 + g4 * 4 + 2];
        float c3 = corr_lds[r * 16 + g4 * 4 + 3];
        #pragma unroll
        for (int v = 0; v < 4; v++) {
          O[r][v][0] *= c0; O[r][v][1] *= c1; O[r][v][2] *= c2; O[r][v][3] *= c3;
        }
      }
    }
  }

  // drain: PV for the last tile
  {
    int tl = tiles_per_g - 1;
    PV_BLOCK(P_lds[tl & 1], V_lds[tl % 3]);
  }
#undef PV_BLOCK

  // write partials
  #pragma unroll
  for (int r = 0; r < 8; r++) {
    #pragma unroll
    for (int v = 0; v < 4; v++) {
      #pragma unroll
      for (int j = 0; j < 4; j++) {
        int n = n0 + r * 16 + g4 * 4 + j;
        int vd = w * 64 + v * 16 + li;
        Op[((size_t)g * NQ + n) * 512 + vd] = O[r][v][j];
      }
    }
  }
  if (li == 0) {
    #pragma unroll
    for (int j = 0; j < 4; j++) {
      int n = n0 + w * 16 + g4 * 4 + j;
      ml[(size_t)g * NQ + n] = make_float2(m[j], s_acc[j]);
    }
  }
}

// ---------------- combine (float4) + AdaAttN epilogue (exp2 domain) ----------------
__global__ __launch_bounds__(256) void combine_kernel(const float* __restrict__ Op, const float2* __restrict__ ml,
                                                      const float* __restrict__ q,
                                                      const float* __restrict__ mq, const float* __restrict__ rq,
                                                      float* __restrict__ out, int G) {
  int t = threadIdx.x;
  int rl = t >> 6, j = t & 63;
  int n = blockIdx.x * 4 + rl, c0 = j * 4;
  __shared__ float wsm[4][8];
  if (j == 0) {
    float mstar = -1e30f;
    float mg[8], lg[8];
    for (int g = 0; g < G; g++) {
      float2 v = ml[(size_t)g * NQ + n];
      mg[g] = v.x; lg[g] = v.y;
      mstar = fmaxf(mstar, v.x);
    }
    float L = 0.f;
    for (int g = 0; g < G; g++) L += lg[g] * exp2f(mg[g] - mstar);
    float Li = 1.f / L;
    for (int g = 0; g < G; g++) wsm[rl][g] = exp2f(mg[g] - mstar) * Li;
  }
  __syncthreads();
  float4 of = make_float4(0, 0, 0, 0), o2 = make_float4(0, 0, 0, 0);
  for (int g = 0; g < G; g++) {
    size_t base = ((size_t)g * NQ + n) * 512;
    float wg = wsm[rl][g];
    float4 a = *(const float4*)(Op + base + c0);
    float4 b = *(const float4*)(Op + base + 256 + c0);
    of.x += wg * a.x; of.y += wg * a.y; of.z += wg * a.z; of.w += wg * a.w;
    o2.x += wg * b.x; o2.y += wg * b.y; o2.z += wg * b.z; o2.w += wg * b.w;
  }
  float4 qv = *(const float4*)(q + (size_t)n * CDIM + c0);
  float4 mv = *(const float4*)(mq + c0);
  float4 rv = *(const float4*)(rq + c0);
  float4 ov;
  ov.x = (qv.x - mv.x) * rv.x * sqrtf(fmaxf(o2.x - of.x * of.x, 0.f)) + of.x;
  ov.y = (qv.y - mv.y) * rv.y * sqrtf(fmaxf(o2.y - of.y * of.y, 0.f)) + of.y;
  ov.z = (qv.z - mv.z) * rv.z * sqrtf(fmaxf(o2.z - of.z * of.z, 0.f)) + of.z;
  ov.w = (qv.w - mv.w) * rv.w * sqrtf(fmaxf(o2.w - of.w * of.w, 0.f)) + of.w;
  *(float4*)(out + (size_t)n * CDIM + c0) = ov;
}

extern "C" void kernel_launch(void* const* d_in, const int* in_sizes, int n_in,
                              void* d_out, int out_size, void* d_ws, size_t ws_size,
                              hipStream_t stream) {
  const float* q  = (const float*)d_in[0];
  const float* k0 = (const float*)d_in[1];
  const float* qw = (const float*)d_in[2];
  const float* qb = (const float*)d_in[3];
  const float* kw = (const float*)d_in[4];
  const float* kb = (const float*)d_in[5];
  const float* sw = (const float*)d_in[6];
  const float* sb = (const float*)d_in[7];
  float* out = (float*)d_out;

  char* ws = (char*)d_ws;
  float* mq   = (float*)ws; ws += 1024;
  float* rq   = (float*)ws; ws += 1024;
  float* mk   = (float*)ws; ws += 1024;
  float* rk   = (float*)ws; ws += 1024;
  float* pq   = (float*)ws; ws += 256 * 256 * 4;
  float* pq2  = (float*)ws; ws += 256 * 256 * 4;
  unsigned short* qwb = (unsigned short*)ws; ws += 65536 * 2;
  unsigned short* kwb = (unsigned short*)ws; ws += 65536 * 2;
  unsigned short* swb = (unsigned short*)ws; ws += 65536 * 2;
  unsigned short* Qs    = (unsigned short*)ws; ws += (size_t)NQ * CDIM * 2;
  unsigned short* stn   = (unsigned short*)ws; ws += (size_t)HWN * CDIM * 2;
  unsigned short* Km    = (unsigned short*)ws; ws += (size_t)HWN * CDIM * 2;
  unsigned short* VseT  = (unsigned short*)ws; ws += (size_t)HWN * CDIM * 2;
  unsigned short* Vse2T = (unsigned short*)ws; ws += (size_t)HWN * CDIM * 2;

  // stT carved from the workspace TAIL: dead before attn writes Op there (order-safe).
  unsigned short* stT = (unsigned short*)((char*)d_ws +
                          ((ws_size - (size_t)HWN * CDIM * 2) & ~(size_t)15));

  size_t base_used = (size_t)(ws - (char*)d_ws);
  int G = 4;
  const int gcand[3] = {4, 2, 1};
  for (int i = 0; i < 3; i++) {
    G = gcand[i];
    size_t need = base_used + (size_t)G * ((size_t)NQ * 512 * 4 + (size_t)NQ * 8);
    if (need <= ws_size) break;
  }
  float*  Opart = (float*)ws;                 ws += (size_t)G * NQ * 512 * 4;
  float2* mlp   = (float2*)ws;                ws += (size_t)G * NQ * 8;
  int tiles_per_g = (HWN / 32) / G;

  stats_all_kernel<<<512, 256, 0, stream>>>(q, k0, pq, pq2, mk, rk);
  cvtall_kernel<<<193, 256, 0, stream>>>(qw, kw, sw, qwb, kwb, swb, pq, pq2, mq, rq);
  ktrans_kernel<<<dim3(HWN / 32, CDIM / 32), 256, 0, stream>>>(k0, mk, rk, stT, stn);
  gemms_kernel<<<416, 256, 0, stream>>>(q, mq, rq, qwb, qb, Qs, stn, kwb, kb, Km, swb, sb, stT, VseT, Vse2T);
  attn_kernel<<<dim3(64 * G), 512, 0, stream>>>(Qs, Km, VseT, Vse2T, Opart, mlp, tiles_per_g, G);
  combine_kernel<<<NQ / 4, 256, 0, stream>>>(Opart, mlp, q, mq, rq, out, G);
}